// Round 1
// baseline (32.324 us; speedup 1.0000x reference)
//
#include <hip/hip_runtime.h>

#define BLOCK 256
#define GRID_A 2048

// Practical Salinity from conductivity only (T, P are dead args in the reference).
__device__ __forceinline__ float sp_from_c(float C) {
    float rt = sqrtf(C / 42.914f);
    float s = ((((0.27081f * rt - 0.70261f) * rt + 0.14692f) * rt
                + (0.025986f - 0.0060269f * rt) * rt) * rt + 0.35f) * rt;
    return s * 35.0f;
}

__device__ __forceinline__ double sq_err(float c, float sref) {
    float e = sp_from_c(c) - sref;
    return (double)(e * e);
}

__global__ __launch_bounds__(BLOCK) void loss_partial_kernel(
    const float4* __restrict__ Cd, const float4* __restrict__ Sd,
    const float4* __restrict__ Cu, const float4* __restrict__ Su,
    double* __restrict__ partials, int n4)
{
    double acc = 0.0;
    int stride = gridDim.x * blockDim.x;
    for (int i = blockIdx.x * blockDim.x + threadIdx.x; i < n4; i += stride) {
        float4 cd = Cd[i];
        float4 sd = Sd[i];
        float4 cu = Cu[i];
        float4 su = Su[i];
        acc += sq_err(cd.x, sd.x) + sq_err(cu.x, su.x);
        acc += sq_err(cd.y, sd.y) + sq_err(cu.y, su.y);
        acc += sq_err(cd.z, sd.z) + sq_err(cu.z, su.z);
        acc += sq_err(cd.w, sd.w) + sq_err(cu.w, su.w);
    }
    __shared__ double sm[BLOCK];
    sm[threadIdx.x] = acc;
    __syncthreads();
    #pragma unroll
    for (int off = BLOCK / 2; off > 0; off >>= 1) {
        if (threadIdx.x < off) sm[threadIdx.x] += sm[threadIdx.x + off];
        __syncthreads();
    }
    if (threadIdx.x == 0) partials[blockIdx.x] = sm[0];
}

__global__ __launch_bounds__(BLOCK) void loss_final_kernel(
    const double* __restrict__ partials, int nparts,
    const float* __restrict__ Cd, const float* __restrict__ Sd,
    const float* __restrict__ Cu, const float* __restrict__ Su,
    int tail_start, int n_total,
    const float* __restrict__ params, int nparams,
    float* __restrict__ out)
{
    int tid = threadIdx.x;
    double acc = 0.0;
    for (int i = tid; i < nparts; i += BLOCK) acc += partials[i];
    // scalar tail (n_total not divisible by 4; zero iterations for this problem)
    for (int i = tail_start + tid; i < n_total; i += BLOCK) {
        acc += sq_err(Cd[i], Sd[i]) + sq_err(Cu[i], Su[i]);
    }
    double pacc = 0.0;
    for (int i = tid; i < nparams; i += BLOCK) {
        double v = (double)params[i];
        pacc += v * v;
    }
    __shared__ double sm[BLOCK];
    __shared__ double sp[BLOCK];
    sm[tid] = acc;
    sp[tid] = pacc;
    __syncthreads();
    #pragma unroll
    for (int off = BLOCK / 2; off > 0; off >>= 1) {
        if (tid < off) { sm[tid] += sm[tid + off]; sp[tid] += sp[tid + off]; }
        __syncthreads();
    }
    if (tid == 0) {
        double loss = sm[0] / (double)n_total + 0.001 * (sp[0] / (double)nparams);
        out[0] = (float)loss;
    }
}

extern "C" void kernel_launch(void* const* d_in, const int* in_sizes, int n_in,
                              void* d_out, int out_size, void* d_ws, size_t ws_size,
                              hipStream_t stream) {
    const float* params = (const float*)d_in[0];   // [B,8]
    const float* Cd     = (const float*)d_in[2];   // C_down
    const float* Cu     = (const float*)d_in[6];   // C_up
    const float* Sd     = (const float*)d_in[9];   // S_ctd_down
    const float* Su     = (const float*)d_in[10];  // S_ctd_up

    int N = in_sizes[1];        // B*S = 8388608
    int nparams = in_sizes[0];  // B*8 = 256
    int n4 = N >> 2;
    int tail_start = n4 << 2;

    double* partials = (double*)d_ws;  // GRID_A doubles = 16 KiB

    loss_partial_kernel<<<GRID_A, BLOCK, 0, stream>>>(
        (const float4*)Cd, (const float4*)Sd,
        (const float4*)Cu, (const float4*)Su,
        partials, n4);

    loss_final_kernel<<<1, BLOCK, 0, stream>>>(
        partials, GRID_A,
        Cd, Sd, Cu, Su, tail_start, N,
        params, nparams,
        (float*)d_out);
}

// Round 2
// 29.272 us; speedup vs baseline: 1.1043x; 1.1043x over previous
//
#include <hip/hip_runtime.h>

#define BLOCK 256
#define GRID_A 2048

// Practical Salinity from conductivity only (T, P are dead args in the reference).
// Division replaced by reciprocal-multiply; sqrt via raw v_sqrt_f32 (~1 ULP,
// threshold is 2% of a ~1672 loss -> enormous headroom).
__device__ __forceinline__ float sp_from_c(float C) {
#if __has_builtin(__builtin_amdgcn_sqrtf)
    float rt = __builtin_amdgcn_sqrtf(C * (1.0f / 42.914f));
#else
    float rt = sqrtf(C * (1.0f / 42.914f));
#endif
    float s = ((((0.27081f * rt - 0.70261f) * rt + 0.14692f) * rt
                + (0.025986f - 0.0060269f * rt) * rt) * rt + 0.35f) * rt;
    return s * 35.0f;
}

__device__ __forceinline__ float sq_err_f(float c, float sref) {
    float e = sp_from_c(c) - sref;
    return e * e;
}

__global__ __launch_bounds__(BLOCK) void loss_partial_kernel(
    const float4* __restrict__ Cd, const float4* __restrict__ Sd,
    const float4* __restrict__ Cu, const float4* __restrict__ Su,
    double* __restrict__ partials, int n4)
{
    double acc = 0.0;
    int stride = gridDim.x * blockDim.x;
    for (int i = blockIdx.x * blockDim.x + threadIdx.x; i < n4; i += stride) {
        float4 cd = Cd[i];
        float4 sd = Sd[i];
        float4 cu = Cu[i];
        float4 su = Su[i];
        // f32 partial for this iteration (8 terms, each O(1e3) -> exact enough),
        // one f64 add per iteration instead of eight dependent ones.
        float t = sq_err_f(cd.x, sd.x) + sq_err_f(cu.x, su.x)
                + sq_err_f(cd.y, sd.y) + sq_err_f(cu.y, su.y)
                + sq_err_f(cd.z, sd.z) + sq_err_f(cu.z, su.z)
                + sq_err_f(cd.w, sd.w) + sq_err_f(cu.w, su.w);
        acc += (double)t;
    }
    __shared__ double sm[BLOCK];
    sm[threadIdx.x] = acc;
    __syncthreads();
    #pragma unroll
    for (int off = BLOCK / 2; off > 0; off >>= 1) {
        if (threadIdx.x < off) sm[threadIdx.x] += sm[threadIdx.x + off];
        __syncthreads();
    }
    if (threadIdx.x == 0) partials[blockIdx.x] = sm[0];
}

__global__ __launch_bounds__(BLOCK) void loss_final_kernel(
    const double* __restrict__ partials, int nparts,
    const float* __restrict__ Cd, const float* __restrict__ Sd,
    const float* __restrict__ Cu, const float* __restrict__ Su,
    int tail_start, int n_total,
    const float* __restrict__ params, int nparams,
    float* __restrict__ out)
{
    int tid = threadIdx.x;
    double acc = 0.0;
    for (int i = tid; i < nparts; i += BLOCK) acc += partials[i];
    // scalar tail (zero iterations for this problem's sizes)
    for (int i = tail_start + tid; i < n_total; i += BLOCK) {
        acc += (double)(sq_err_f(Cd[i], Sd[i]) + sq_err_f(Cu[i], Su[i]));
    }
    double pacc = 0.0;
    for (int i = tid; i < nparams; i += BLOCK) {
        double v = (double)params[i];
        pacc += v * v;
    }
    __shared__ double sm[BLOCK];
    __shared__ double sp[BLOCK];
    sm[tid] = acc;
    sp[tid] = pacc;
    __syncthreads();
    #pragma unroll
    for (int off = BLOCK / 2; off > 0; off >>= 1) {
        if (tid < off) { sm[tid] += sm[tid + off]; sp[tid] += sp[tid + off]; }
        __syncthreads();
    }
    if (tid == 0) {
        double loss = sm[0] / (double)n_total + 0.001 * (sp[0] / (double)nparams);
        out[0] = (float)loss;
    }
}

extern "C" void kernel_launch(void* const* d_in, const int* in_sizes, int n_in,
                              void* d_out, int out_size, void* d_ws, size_t ws_size,
                              hipStream_t stream) {
    const float* params = (const float*)d_in[0];   // [B,8]
    const float* Cd     = (const float*)d_in[2];   // C_down
    const float* Cu     = (const float*)d_in[6];   // C_up
    const float* Sd     = (const float*)d_in[9];   // S_ctd_down
    const float* Su     = (const float*)d_in[10];  // S_ctd_up

    int N = in_sizes[1];        // B*S = 8388608
    int nparams = in_sizes[0];  // B*8 = 256
    int n4 = N >> 2;
    int tail_start = n4 << 2;

    double* partials = (double*)d_ws;  // GRID_A doubles = 16 KiB

    loss_partial_kernel<<<GRID_A, BLOCK, 0, stream>>>(
        (const float4*)Cd, (const float4*)Sd,
        (const float4*)Cu, (const float4*)Su,
        partials, n4);

    loss_final_kernel<<<1, BLOCK, 0, stream>>>(
        partials, GRID_A,
        Cd, Sd, Cu, Su, tail_start, N,
        params, nparams,
        (float*)d_out);
}